// Round 3
// baseline (419.267 us; speedup 1.0000x reference)
//
#include <hip/hip_runtime.h>

// SoftTriple loss, MI355X. B=256, E=512, C=8192, K=10.
// Normalization folded into GEMM epilogue (x = (emb.fc^T) * invn).
// ws layout (bytes):
//   [0, 83886080)            w bf16 [81920][512]  (raw cast, unnormalized)
//   [83886080, 84148224)     embb bf16 [256][512]
//   [84148224, 92536832)     hT float [8192][256]
//   [92536832, 93061120)     invn float [8192][16] (pad k>=10 zero)
//   [93061120, 93093888)     gram_part float[8192]
//   [93093888, 93159424)     part_m float[64][256]
//   [93159424, 93224960)     part_s float[64][256]

typedef __bf16 bf16;
typedef bf16 bf16x8 __attribute__((ext_vector_type(8)));
typedef bf16 bf16x4 __attribute__((ext_vector_type(4)));
typedef bf16 bf16x2 __attribute__((ext_vector_type(2)));
typedef float f32x4 __attribute__((ext_vector_type(4)));

#define NCLASS 8192
#define KC 10
#define EDIM 512
#define BATCH 256

// ---------------- kernel 1: per-class cast + invn + gram ------------------
// 320 threads = 5 waves; class c per block. Single pass over fc.
__global__ __launch_bounds__(320) void prep_kernel(
    const float* __restrict__ fc, bf16* __restrict__ w,
    float* __restrict__ invn, float* __restrict__ gram_part)
{
    __shared__ bf16 rb[KC * EDIM];     // 10 KB, bf16 copy of the class rows
    __shared__ float s_invn[KC];
    __shared__ float s_part[5];
    const int c = blockIdx.x, t = threadIdx.x;
    const int wave = t >> 6, lane = t & 63;

    // phase 1: stream fp32 in (lane-contiguous float4), cast, write bf16 out
    // (lane-contiguous 8B stores) and stash bf16 copy in LDS (8B, 4-way ok).
    const float4* src = (const float4*)(fc + (size_t)c * (KC * EDIM));
    bf16x4* wdst = (bf16x4*)(w + (size_t)c * (KC * EDIM));
    bf16x4* ldst = (bf16x4*)rb;
    #pragma unroll
    for (int p = 0; p < 4; ++p) {
        int idx = t + p * 320;          // 1280 float4 total
        float4 v = src[idx];
        bf16x4 bv;
        bv[0] = (bf16)v.x; bv[1] = (bf16)v.y;
        bv[2] = (bf16)v.z; bv[3] = (bf16)v.w;
        ldst[idx] = bv;
        wdst[idx] = bv;
    }
    __syncthreads();

    // phase 2: row norms from bf16 (consistent with what GEMM consumes).
    // wave w handles rows 2w, 2w+1. bf16x2 reads: 4B lane stride, no conflict.
    #pragma unroll
    for (int rr = 0; rr < 2; ++rr) {
        int r = wave * 2 + rr;
        float s = 0.f;
        #pragma unroll
        for (int j = 0; j < 4; ++j) {
            bf16x2 v = *(const bf16x2*)&rb[r * EDIM + (lane + j * 64) * 2];
            float a = (float)v[0], b = (float)v[1];
            s += a * a + b * b;
        }
        #pragma unroll
        for (int off = 32; off; off >>= 1) s += __shfl_xor(s, off);
        if (lane == 0) s_invn[r] = 1.0f / fmaxf(sqrtf(s), 1e-12f);
    }
    __syncthreads();
    if (t < 16) invn[(size_t)c * 16 + t] = (t < KC) ? s_invn[t] : 0.0f;

    // phase 3: gram, 9 pairs per wave (5*9 = 45 strict-upper pairs)
    float part = 0.f;
    #pragma unroll
    for (int q = 0; q < 9; ++q) {
        int p = wave * 9 + q;
        int i = 0, pp = p;
        while (pp >= 9 - i) { pp -= 9 - i; ++i; }
        int j = i + 1 + pp;
        float s = 0.f;
        #pragma unroll
        for (int u = 0; u < 4; ++u) {
            bf16x2 a = *(const bf16x2*)&rb[i * EDIM + (lane + u * 64) * 2];
            bf16x2 b = *(const bf16x2*)&rb[j * EDIM + (lane + u * 64) * 2];
            s += (float)a[0] * (float)b[0] + (float)a[1] * (float)b[1];
        }
        #pragma unroll
        for (int off = 32; off; off >>= 1) s += __shfl_xor(s, off);
        if (lane == 0) {
            float sub = 1.0f - s * s_invn[i] * s_invn[j];
            if (sub <= 0.f) sub = 1e-10f;
            part += sqrtf(2.0f * sub);
        }
    }
    if (lane == 0) s_part[wave] = part;
    __syncthreads();
    if (t == 0)
        gram_part[c] = s_part[0] + s_part[1] + s_part[2] + s_part[3] + s_part[4];
}

// ---------------- kernel 1b: embeddings fp32 -> bf16 ----------------------
__global__ __launch_bounds__(256) void conv_kernel(
    const float* __restrict__ e, bf16* __restrict__ out)
{
    int i = blockIdx.x * 256 + threadIdx.x;   // 64 blocks * 256 * 8 = 131072
    float4 a = ((const float4*)e)[i * 2];
    float4 b = ((const float4*)e)[i * 2 + 1];
    bf16x8 v;
    v[0] = (bf16)a.x; v[1] = (bf16)a.y; v[2] = (bf16)a.z; v[3] = (bf16)a.w;
    v[4] = (bf16)b.x; v[5] = (bf16)b.y; v[6] = (bf16)b.z; v[7] = (bf16)b.w;
    ((bf16x8*)out)[i] = v;
}

// ---------------- kernel 2: register-direct GEMM + softmax-K epilogue -----
// No LDS, no barriers. Block = 4 classes x full batch; 4 waves = 4 batch
// quarters. Wave = 64x64 = 4x4 MFMA 16x16x32 tiles. A-operand = W rows
// (unpadded; pad k in [10,16) clamps to row 0, masked in epilogue).
__global__ __launch_bounds__(256) void gemm_h_kernel(
    const bf16* __restrict__ w, const bf16* __restrict__ embb,
    const float* __restrict__ invn, float* __restrict__ hT)
{
    const int tid = threadIdx.x;
    const int wave = tid >> 6, lane = tid & 63;
    const int m16 = lane & 15, quad = lane >> 4;
    const int cgrp = blockIdx.x;              // 2048 groups of 4 classes
    const int clamp_m = (m16 < KC) ? m16 : 0;

    const bf16* wp[4];
    const bf16* ep[4];
    #pragma unroll
    for (int mt = 0; mt < 4; ++mt)
        wp[mt] = w + ((size_t)(cgrp * 4 + mt) * KC + clamp_m) * EDIM + quad * 8;
    #pragma unroll
    for (int nt = 0; nt < 4; ++nt)
        ep[nt] = embb + (size_t)(wave * 64 + nt * 16 + m16) * EDIM + quad * 8;

    f32x4 acc[4][4];
    #pragma unroll
    for (int mt = 0; mt < 4; ++mt)
        #pragma unroll
        for (int nt = 0; nt < 4; ++nt)
            acc[mt][nt] = (f32x4){0.f, 0.f, 0.f, 0.f};

    #pragma unroll
    for (int kb = 0; kb < EDIM; kb += 32) {
        bf16x8 wf[4], ef[4];
        #pragma unroll
        for (int mt = 0; mt < 4; ++mt)
            wf[mt] = *(const bf16x8*)(wp[mt] + kb);
        #pragma unroll
        for (int nt = 0; nt < 4; ++nt)
            ef[nt] = *(const bf16x8*)(ep[nt] + kb);
        #pragma unroll
        for (int mt = 0; mt < 4; ++mt)
            #pragma unroll
            for (int nt = 0; nt < 4; ++nt)
                acc[mt][nt] = __builtin_amdgcn_mfma_f32_16x16x32_bf16(
                    wf[mt], ef[nt], acc[mt][nt], 0, 0, 0);
    }

    // epilogue: D row = quad*4+r = k (pad masked), D col = lane&15 = batch
    #pragma unroll
    for (int mt = 0; mt < 4; ++mt) {
        int cls = cgrp * 4 + mt;
        float4 iv = *(const float4*)(invn + (size_t)cls * 16 + quad * 4);
        #pragma unroll
        for (int nt = 0; nt < 4; ++nt) {
            float x[4];
            float xm = -1e30f;
            #pragma unroll
            for (int r = 0; r < 4; ++r) {
                x[r] = acc[mt][nt][r] * ((const float*)&iv)[r];
                if (quad * 4 + r < KC) xm = fmaxf(xm, x[r]);
            }
            xm = fmaxf(xm, __shfl_xor(xm, 16));
            xm = fmaxf(xm, __shfl_xor(xm, 32));
            float s1 = 0.f, s2 = 0.f;
            #pragma unroll
            for (int r = 0; r < 4; ++r) {
                if (quad * 4 + r < KC) {
                    float e = __expf(10.0f * (x[r] - xm));
                    s1 += e; s2 += e * x[r];
                }
            }
            s1 += __shfl_xor(s1, 16); s1 += __shfl_xor(s1, 32);
            s2 += __shfl_xor(s2, 16); s2 += __shfl_xor(s2, 32);
            if (quad == 0)
                hT[(size_t)cls * BATCH + wave * 64 + nt * 16 + m16] = s2 / s1;
        }
    }
}

// ---------------- kernel 3: CE slices (online logsumexp over 128 classes) -
__global__ __launch_bounds__(256) void ce_kernel(
    const float* __restrict__ hT, const int* __restrict__ labels,
    float* __restrict__ part_m, float* __restrict__ part_s)
{
    const int s = blockIdx.x, b = threadIdx.x;
    const int lbl = labels[b];
    const int c0 = s * 128;
    float m = -1e30f, sum = 0.f;
    for (int i = 0; i < 128; ++i) {
        int c = c0 + i;
        float x = 10.0f * hT[(size_t)c * BATCH + b];
        if (c == lbl) x -= 0.1f;               // LMD * MARGIN
        if (x > m) { sum = sum * __expf(m - x) + 1.0f; m = x; }
        else sum += __expf(x - m);
    }
    part_m[s * BATCH + b] = m;
    part_s[s * BATCH + b] = sum;
}

// ---------------- kernel 4: merge slices + gram reduce + combine ----------
__global__ __launch_bounds__(256) void final_kernel(
    const float* __restrict__ part_m, const float* __restrict__ part_s,
    const float* __restrict__ hT, const int* __restrict__ labels,
    const float* __restrict__ gram_part, float* __restrict__ out)
{
    __shared__ float red[4];
    const int t = threadIdx.x, wave = t >> 6, lane = t & 63;
    float M = -1e30f, S = 0.f;
    for (int s = 0; s < 64; ++s) {
        float m = part_m[s * BATCH + t], ss = part_s[s * BATCH + t];
        if (m > M) { S = S * __expf(M - m) + ss; M = m; }
        else S += ss * __expf(m - M);
    }
    int lbl = labels[t];
    float xl = 10.0f * hT[(size_t)lbl * BATCH + t] - 0.1f;
    float ce = M + logf(S) - xl;               // -logp[label]
    float g = 0.f;
    #pragma unroll
    for (int i = 0; i < 32; ++i) g += gram_part[t + i * 256];
    float val = ce * (1.0f / 256.0f) + g * (0.2f / 737280.0f);
    #pragma unroll
    for (int off = 32; off; off >>= 1) val += __shfl_xor(val, off);
    if (lane == 0) red[wave] = val;
    __syncthreads();
    if (t == 0) out[0] = red[0] + red[1] + red[2] + red[3];
}

extern "C" void kernel_launch(void* const* d_in, const int* in_sizes, int n_in,
                              void* d_out, int out_size, void* d_ws, size_t ws_size,
                              hipStream_t stream) {
    const float* emb    = (const float*)d_in[0];   // [256][512]
    const int*   labels = (const int*)d_in[1];     // [256]
    const float* fc     = (const float*)d_in[2];   // [81920][512]
    float* out = (float*)d_out;

    char* ws = (char*)d_ws;
    bf16*  w         = (bf16*)ws;                        // 83886080 B
    bf16*  embb      = (bf16*)(ws + 83886080);           //   262144 B
    float* hT        = (float*)(ws + 84148224);          //  8388608 B
    float* invn      = (float*)(ws + 92536832);          //   524288 B
    float* gram_part = (float*)(ws + 93061120);          //    32768 B
    float* part_m    = (float*)(ws + 93093888);          //    65536 B
    float* part_s    = (float*)(ws + 93159424);          //    65536 B

    prep_kernel<<<NCLASS, 320, 0, stream>>>(fc, w, invn, gram_part);
    conv_kernel<<<64, 256, 0, stream>>>(emb, embb);
    gemm_h_kernel<<<2048, 256, 0, stream>>>(w, embb, invn, hT);
    ce_kernel<<<64, 256, 0, stream>>>(hT, labels, part_m, part_s);
    final_kernel<<<1, 256, 0, stream>>>(part_m, part_s, hT, labels, gram_part, out);
}

// Round 4
// 339.797 us; speedup vs baseline: 1.2339x; 1.2339x over previous
//
#include <hip/hip_runtime.h>

// SoftTriple loss, MI355X. B=256, E=512, C=8192, K=10.
// Single pass over fc: fused cast+norm+gram+GEMM+softmax-K kernel.
// ws layout (bytes):
//   [0, 262144)          embb bf16 [256][512]
//   [262144, 8650752)    hT float [8192][256]
//   [8650752, 8658944)   gram_part float[2048]
//   [8658944, 8724480)   part_m float[64][256]
//   [8724480, 8790016)   part_s float[64][256]

typedef __bf16 bf16;
typedef bf16 bf16x8 __attribute__((ext_vector_type(8)));
typedef bf16 bf16x4 __attribute__((ext_vector_type(4)));
typedef float f32x4 __attribute__((ext_vector_type(4)));

#define NCLASS 8192
#define KC 10
#define EDIM 512
#define BATCH 256
#define CPB 4          // classes per block
#define WST 520        // LDS W row stride in bf16 (padded: 1040 B breaks bank aliasing)

__device__ inline void load_lds16(const void* g, void* l) {
    __builtin_amdgcn_global_load_lds(
        (const __attribute__((address_space(1))) void*)g,
        (__attribute__((address_space(3))) void*)l, 16, 0, 0);
}

// ---------------- kernel 1: embeddings fp32 -> bf16 -----------------------
__global__ __launch_bounds__(256) void conv_kernel(
    const float* __restrict__ e, bf16* __restrict__ out)
{
    int i = blockIdx.x * 256 + threadIdx.x;   // 64 blocks * 256 * 8 = 131072
    float4 a = ((const float4*)e)[i * 2];
    float4 b = ((const float4*)e)[i * 2 + 1];
    bf16x8 v;
    v[0] = (bf16)a.x; v[1] = (bf16)a.y; v[2] = (bf16)a.z; v[3] = (bf16)a.w;
    v[4] = (bf16)b.x; v[5] = (bf16)b.y; v[6] = (bf16)b.z; v[7] = (bf16)b.w;
    ((bf16x8*)out)[i] = v;
}

// ---------------- kernel 2: fused cast+gram+GEMM+softmax ------------------
// 2048 blocks x 4 classes; 256 threads = 4 waves; wave = 64-batch slice.
// LDS: Wt 41600 B + Es 32768 B -> 2 blocks/CU.
__global__ __launch_bounds__(256, 2) void fused_kernel(
    const float* __restrict__ fc, const bf16* __restrict__ embb,
    float* __restrict__ hT, float* __restrict__ gram_part)
{
    __shared__ bf16 Wt[CPB * KC * WST];      // 40 rows x 520, 41600 B
    __shared__ bf16 Es[2 * 256 * 32];        // two [256][32] half-K buffers
    __shared__ float s_invn[CPB * 16];       // per-class invn, pad zeros
    __shared__ float s_part[CPB];

    const int t = threadIdx.x;
    const int wave = t >> 6, lane = t & 63;
    const int m16 = lane & 15, quad = lane >> 4;
    const int c0 = blockIdx.x * CPB;
    const int clamp_m = (m16 < KC) ? m16 : 0;

    // ---- phase A: stream 40 rows x 512 fp32, cast, stash bf16 in LDS ----
    const float4* src = (const float4*)(fc + (size_t)c0 * (KC * EDIM));
    #pragma unroll
    for (int p = 0; p < 20; ++p) {
        int idx = t + p * 256;               // 5120 float4 total
        int row = idx >> 7, col = idx & 127; // 128 float4 per row
        float4 v = src[idx];
        bf16x4 bv;
        bv[0] = (bf16)v.x; bv[1] = (bf16)v.y;
        bv[2] = (bf16)v.z; bv[3] = (bf16)v.w;
        *(bf16x4*)&Wt[row * WST + col * 4] = bv;
    }
    __syncthreads();

    // ---- stage Es(kb=0) now; DMA overlaps phase B compute ----
    const int lrow = lane >> 2, lcol = (lane & 3) * 8;
    #pragma unroll
    for (int h = 0; h < 2; ++h)
        #pragma unroll
        for (int p = 0; p < 4; ++p) {
            int r0 = wave * 64 + p * 16;
            load_lds16(embb + (size_t)(r0 + lrow) * EDIM + h * 32 + lcol,
                       Es + h * 8192 + r0 * 32);
        }

    // ---- phase B: gram of class (c0+wave) via MFMA; diag = norms ----
    {
        f32x4 g = (f32x4){0.f, 0.f, 0.f, 0.f};
        #pragma unroll
        for (int kb = 0; kb < 16; ++kb) {
            bf16x8 f = *(const bf16x8*)
                &Wt[(wave * KC + clamp_m) * WST + kb * 32 + quad * 8];
            g = __builtin_amdgcn_mfma_f32_16x16x32_bf16(f, f, g, 0, 0, 0);
        }
        // D row = quad*4+r, D col = m16. Diagonal (r==c) -> invn.
        #pragma unroll
        for (int r = 0; r < 4; ++r) {
            int row = quad * 4 + r;
            if (row == m16 && m16 < KC)
                s_invn[wave * 16 + m16] = 1.0f / fmaxf(sqrtf(g[r]), 1e-12f);
        }
        if (lane >= KC && lane < 16) s_invn[wave * 16 + lane] = 0.f;
        // strict-upper pairs (row < col < KC): each counted exactly once
        float part = 0.f;
        #pragma unroll
        for (int r = 0; r < 4; ++r) {
            int row = quad * 4 + r, col = m16;
            if (row < col && col < KC) {
                float sub = 1.0f - g[r] * s_invn[wave * 16 + row]
                                        * s_invn[wave * 16 + col];
                if (sub <= 0.f) sub = 1e-10f;
                part += sqrtf(2.0f * sub);
            }
        }
        #pragma unroll
        for (int off = 32; off; off >>= 1) part += __shfl_xor(part, off);
        if (lane == 0) s_part[wave] = part;
    }

    f32x4 acc[4][4];
    #pragma unroll
    for (int mt = 0; mt < 4; ++mt)
        #pragma unroll
        for (int nt = 0; nt < 4; ++nt)
            acc[mt][nt] = (f32x4){0.f, 0.f, 0.f, 0.f};

    __syncthreads();   // Es(0) DMA drained, s_invn/s_part visible

    // ---- K-loop: BK=64 (two 32-halves), 8 iterations ----
    #pragma unroll
    for (int kb = 0; kb < 8; ++kb) {
        bf16x8 wf[2][4], ef[2][4];
        #pragma unroll
        for (int h = 0; h < 2; ++h) {
            #pragma unroll
            for (int mt = 0; mt < 4; ++mt)
                wf[h][mt] = *(const bf16x8*)
                    &Wt[(mt * KC + clamp_m) * WST + kb * 64 + h * 32 + quad * 8];
            #pragma unroll
            for (int nt = 0; nt < 4; ++nt)
                ef[h][nt] = *(const bf16x8*)
                    &Es[h * 8192 + (wave * 64 + nt * 16 + m16) * 32 + quad * 8];
        }
        #pragma unroll
        for (int mt = 0; mt < 4; ++mt)
            #pragma unroll
            for (int nt = 0; nt < 4; ++nt) {
                acc[mt][nt] = __builtin_amdgcn_mfma_f32_16x16x32_bf16(
                    wf[0][mt], ef[0][nt], acc[mt][nt], 0, 0, 0);
                acc[mt][nt] = __builtin_amdgcn_mfma_f32_16x16x32_bf16(
                    wf[1][mt], ef[1][nt], acc[mt][nt], 0, 0, 0);
            }
        if (kb < 7) {
            __syncthreads();   // everyone done reading Es(kb)
            #pragma unroll
            for (int h = 0; h < 2; ++h)
                #pragma unroll
                for (int p = 0; p < 4; ++p) {
                    int r0 = wave * 64 + p * 16;
                    load_lds16(embb + (size_t)(r0 + lrow) * EDIM
                                   + (kb + 1) * 64 + h * 32 + lcol,
                               Es + h * 8192 + r0 * 32);
                }
            __syncthreads();   // Es(kb+1) ready
        }
    }

    // ---- epilogue: scale by invn, k-softmax (rows quad*4+r, pad masked) --
    #pragma unroll
    for (int mt = 0; mt < 4; ++mt) {
        int cls = c0 + mt;
        float4 iv = *(const float4*)&s_invn[mt * 16 + quad * 4];
        #pragma unroll
        for (int nt = 0; nt < 4; ++nt) {
            float x[4];
            float xm = -1e30f;
            #pragma unroll
            for (int r = 0; r < 4; ++r) {
                x[r] = acc[mt][nt][r] * ((const float*)&iv)[r];
                if (quad * 4 + r < KC) xm = fmaxf(xm, x[r]);
            }
            xm = fmaxf(xm, __shfl_xor(xm, 16));
            xm = fmaxf(xm, __shfl_xor(xm, 32));
            float s1 = 0.f, s2 = 0.f;
            #pragma unroll
            for (int r = 0; r < 4; ++r) {
                if (quad * 4 + r < KC) {
                    float e = __expf(10.0f * (x[r] - xm));
                    s1 += e; s2 += e * x[r];
                }
            }
            s1 += __shfl_xor(s1, 16); s1 += __shfl_xor(s1, 32);
            s2 += __shfl_xor(s2, 16); s2 += __shfl_xor(s2, 32);
            if (quad == 0)
                hT[(size_t)cls * BATCH + wave * 64 + nt * 16 + m16] = s2 / s1;
        }
    }

    if (t == 0)
        gram_part[blockIdx.x] = s_part[0] + s_part[1] + s_part[2] + s_part[3];
}

// ---------------- kernel 3: CE slices (online logsumexp, 128 classes) -----
__global__ __launch_bounds__(256) void ce_kernel(
    const float* __restrict__ hT, const int* __restrict__ labels,
    float* __restrict__ part_m, float* __restrict__ part_s)
{
    const int s = blockIdx.x, b = threadIdx.x;
    const int lbl = labels[b];
    const int c0 = s * 128;
    float m = -1e30f, sum = 0.f;
    for (int i = 0; i < 128; ++i) {
        int c = c0 + i;
        float x = 10.0f * hT[(size_t)c * BATCH + b];
        if (c == lbl) x -= 0.1f;               // LMD * MARGIN
        if (x > m) { sum = sum * __expf(m - x) + 1.0f; m = x; }
        else sum += __expf(x - m);
    }
    part_m[s * BATCH + b] = m;
    part_s[s * BATCH + b] = sum;
}

// ---------------- kernel 4: merge slices + gram reduce + combine ----------
__global__ __launch_bounds__(256) void final_kernel(
    const float* __restrict__ part_m, const float* __restrict__ part_s,
    const float* __restrict__ hT, const int* __restrict__ labels,
    const float* __restrict__ gram_part, float* __restrict__ out)
{
    __shared__ float red[4];
    const int t = threadIdx.x, wave = t >> 6, lane = t & 63;
    float M = -1e30f, S = 0.f;
    for (int s = 0; s < 64; ++s) {
        float m = part_m[s * BATCH + t], ss = part_s[s * BATCH + t];
        if (m > M) { S = S * __expf(M - m) + ss; M = m; }
        else S += ss * __expf(m - M);
    }
    int lbl = labels[t];
    float xl = 10.0f * hT[(size_t)lbl * BATCH + t] - 0.1f;
    float ce = M + logf(S) - xl;               // -logp[label]
    float g = 0.f;
    #pragma unroll
    for (int i = 0; i < 8; ++i) g += gram_part[t + i * 256];
    float val = ce * (1.0f / 256.0f) + g * (0.2f / 737280.0f);  // C*K*(K-1)
    #pragma unroll
    for (int off = 32; off; off >>= 1) val += __shfl_xor(val, off);
    if (lane == 0) red[wave] = val;
    __syncthreads();
    if (t == 0) out[0] = red[0] + red[1] + red[2] + red[3];
}

extern "C" void kernel_launch(void* const* d_in, const int* in_sizes, int n_in,
                              void* d_out, int out_size, void* d_ws, size_t ws_size,
                              hipStream_t stream) {
    const float* emb    = (const float*)d_in[0];   // [256][512]
    const int*   labels = (const int*)d_in[1];     // [256]
    const float* fc     = (const float*)d_in[2];   // [81920][512]
    float* out = (float*)d_out;

    char* ws = (char*)d_ws;
    bf16*  embb      = (bf16*)ws;                        //   262144 B
    float* hT        = (float*)(ws + 262144);            //  8388608 B
    float* gram_part = (float*)(ws + 8650752);           //     8192 B
    float* part_m    = (float*)(ws + 8658944);           //    65536 B
    float* part_s    = (float*)(ws + 8724480);           //    65536 B

    conv_kernel<<<64, 256, 0, stream>>>(emb, embb);
    fused_kernel<<<NCLASS / CPB, 256, 0, stream>>>(fc, embb, hT, gram_part);
    ce_kernel<<<64, 256, 0, stream>>>(hT, labels, part_m, part_s);
    final_kernel<<<1, 256, 0, stream>>>(part_m, part_s, hT, labels, gram_part, out);
}